// Round 7
// baseline (126.419 us; speedup 1.0000x reference)
//
#include <hip/hip_runtime.h>

constexpr int NN = 100000;
constexpr int CH = 128;
constexpr int NE = 625000;
constexpr int NSCAN = (NN + 1023) / 1024;          // 98 scan blocks
constexpr int GEMM_BLOCKS = (NN + 127) / 128;      // 782 (128 rows/block)
constexpr int HIST_BLOCKS = (NE / 4 + 255) / 256;  // 611 (NE % 4 == 0)

typedef __bf16 bf16x8 __attribute__((ext_vector_type(8)));
typedef __bf16 bf16x4 __attribute__((ext_vector_type(4)));
typedef float  f32x4  __attribute__((ext_vector_type(4)));

// ---- fused: MFMA GEMM (blocks < GEMM_BLOCKS) + edge histogram w/ rank ----
// GEMM: xt_bf16 = bf16(x @ W^T + b), 4 waves/block, 32 rows/wave (2 n-tiles).
// Operands swapped vs r5: A = W (m = channel), B = x (n = node row), so
// D reg-quad = 4 consecutive channels of one row -> 8-byte packed stores.
// Hist: rank[e] = atomicAdd(&cnt[dst[e]], 1), 4 edges/thread (ILP-batched).
__global__ __launch_bounds__(256) void gemm_hist_kernel(
    const float* __restrict__ x, const float* __restrict__ W,
    const float* __restrict__ b, __bf16* __restrict__ xt,
    const int* __restrict__ ei, int* __restrict__ cnt, int* __restrict__ rank)
{
    if (blockIdx.x >= GEMM_BLOCKS) {
        const int t = (blockIdx.x - GEMM_BLOCKS) * 256 + threadIdx.x;
        if (t * 4 < NE) {
            int4 d = reinterpret_cast<const int4*>(ei + NE)[t];
            int r0 = atomicAdd(&cnt[d.x], 1);
            int r1 = atomicAdd(&cnt[d.y], 1);
            int r2 = atomicAdd(&cnt[d.z], 1);
            int r3 = atomicAdd(&cnt[d.w], 1);
            reinterpret_cast<int4*>(rank)[t] = make_int4(r0, r1, r2, r3);
        }
        return;
    }

    // W staged as bf16, swizzled: wlds[ch*128 + (k ^ ((ch&7)<<3))]
    __shared__ __bf16 wlds[128 * 128];
    const int tid = threadIdx.x;

    const float4* W4 = reinterpret_cast<const float4*>(W);
    #pragma unroll
    for (int it = 0; it < 16; ++it) {
        int idx = it * 256 + tid;          // 4096 float4 groups, coalesced
        int ch = idx >> 5;
        int k0 = (idx & 31) * 4;
        float4 v = W4[idx];
        __bf16* p = &wlds[ch * 128 + (k0 ^ ((ch & 7) << 3))];
        p[0] = (__bf16)v.x; p[1] = (__bf16)v.y;
        p[2] = (__bf16)v.z; p[3] = (__bf16)v.w;
    }
    __syncthreads();

    const int lane = tid & 63;
    const int lm = lane & 15;          // tile-local row (n) / W channel (m)
    const int lk = lane >> 4;          // k-group / channel-quad selector
    const int row0 = blockIdx.x * 128 + (tid >> 6) * 32;

    const int rowA = row0 + lm;        // n-tile 0
    const int rowB = row0 + 16 + lm;   // n-tile 1
    int ra = rowA < NN ? rowA : NN - 1;
    int rb = rowB < NN ? rowB : NN - 1;
    const float* xrowA = x + (size_t)ra * CH;
    const float* xrowB = x + (size_t)rb * CH;

    bf16x8 bfragA[4], bfragB[4];
    #pragma unroll
    for (int ks = 0; ks < 4; ++ks) {
        const float4* pa = reinterpret_cast<const float4*>(xrowA + ks * 32 + lk * 8);
        const float4* pb = reinterpret_cast<const float4*>(xrowB + ks * 32 + lk * 8);
        float4 u = pa[0], v = pa[1];
        bfragA[ks][0] = (__bf16)u.x; bfragA[ks][1] = (__bf16)u.y;
        bfragA[ks][2] = (__bf16)u.z; bfragA[ks][3] = (__bf16)u.w;
        bfragA[ks][4] = (__bf16)v.x; bfragA[ks][5] = (__bf16)v.y;
        bfragA[ks][6] = (__bf16)v.z; bfragA[ks][7] = (__bf16)v.w;
        u = pb[0]; v = pb[1];
        bfragB[ks][0] = (__bf16)u.x; bfragB[ks][1] = (__bf16)u.y;
        bfragB[ks][2] = (__bf16)u.z; bfragB[ks][3] = (__bf16)u.w;
        bfragB[ks][4] = (__bf16)v.x; bfragB[ks][5] = (__bf16)v.y;
        bfragB[ks][6] = (__bf16)v.z; bfragB[ks][7] = (__bf16)v.w;
    }

    // Bias: lane's channel quad for tile t is t*16 + lk*4 .. +3
    const float4* B4 = reinterpret_cast<const float4*>(b);
    float4 bv[8];
    #pragma unroll
    for (int t = 0; t < 8; ++t) bv[t] = B4[t * 4 + lk];

    const int swz = (lm & 7) << 3;
    #pragma unroll
    for (int t = 0; t < 8; ++t) {
        const int ch = t * 16 + lm;    // A-fragment m index (W channel)
        f32x4 acc0 = {bv[t].x, bv[t].y, bv[t].z, bv[t].w};
        f32x4 acc1 = acc0;
        #pragma unroll
        for (int ks = 0; ks < 4; ++ks) {
            bf16x8 afrag = *reinterpret_cast<const bf16x8*>(
                &wlds[ch * 128 + ((ks * 32 + lk * 8) ^ swz)]);
            acc0 = __builtin_amdgcn_mfma_f32_16x16x32_bf16(afrag, bfragA[ks], acc0, 0, 0, 0);
            acc1 = __builtin_amdgcn_mfma_f32_16x16x32_bf16(afrag, bfragB[ks], acc1, 0, 0, 0);
        }
        // D: col(lane&15) = node row, row((lane>>4)*4+reg) = channel
        const int c0 = t * 16 + lk * 4;
        if (rowA < NN) {
            bf16x4 hv = {(__bf16)acc0[0], (__bf16)acc0[1], (__bf16)acc0[2], (__bf16)acc0[3]};
            *reinterpret_cast<bf16x4*>(&xt[(size_t)rowA * CH + c0]) = hv;
        }
        if (rowB < NN) {
            bf16x4 hv = {(__bf16)acc1[0], (__bf16)acc1[1], (__bf16)acc1[2], (__bf16)acc1[3]};
            *reinterpret_cast<bf16x4*>(&xt[(size_t)rowB * CH + c0]) = hv;
        }
    }
}

// Zero cnt on the compute queue (no SDMA memset node in the graph).
__global__ __launch_bounds__(256) void zero_kernel(int* __restrict__ cnt)
{
    int i = blockIdx.x * 256 + threadIdx.x;
    if (i < NN) cnt[i] = 0;
}

__global__ __launch_bounds__(256) void scan_local_kernel(
    const int* __restrict__ cnt, int* __restrict__ loff,
    int* __restrict__ blocksums)
{
    __shared__ int tsum[256];
    const int t = threadIdx.x;
    const int base = blockIdx.x * 1024 + t * 4;
    int v[4];
    #pragma unroll
    for (int k = 0; k < 4; ++k) {
        int i = base + k;
        v[k] = (i < NN) ? cnt[i] : 0;
    }
    const int s = v[0] + v[1] + v[2] + v[3];
    tsum[t] = s;
    __syncthreads();
    for (int off = 1; off < 256; off <<= 1) {
        int u = (t >= off) ? tsum[t - off] : 0;
        __syncthreads();
        tsum[t] += u;
        __syncthreads();
    }
    int run = tsum[t] - s;
    #pragma unroll
    for (int k = 0; k < 4; ++k) {
        int i = base + k;
        if (i < NN) loff[i] = run;
        run += v[k];
    }
    if (t == 255) blocksums[blockIdx.x] = tsum[255];
}

__global__ __launch_bounds__(128) void scan_blocks_kernel(int* __restrict__ blocksums)
{
    __shared__ int sm[128];
    const int t = threadIdx.x;
    int v = (t < NSCAN) ? blocksums[t] : 0;
    sm[t] = v;
    __syncthreads();
    for (int off = 1; off < 128; off <<= 1) {
        int u = (t >= off) ? sm[t - off] : 0;
        __syncthreads();
        sm[t] += u;
        __syncthreads();
    }
    if (t < NSCAN) blocksums[t] = sm[t] - v;
}

__global__ __launch_bounds__(256) void scan_add_kernel(
    const int* __restrict__ loff, const int* __restrict__ blocksums,
    int* __restrict__ offs)
{
    int i = blockIdx.x * 256 + threadIdx.x;
    if (i > NN) return;
    if (i == NN) { offs[NN] = NE; return; }
    offs[i] = loff[i] + blocksums[i >> 10];
}

// Atomic-free placement: srcs[offs[dst] + rank[e]] = src, 4 edges/thread.
__global__ __launch_bounds__(256) void place_kernel(
    const int* __restrict__ ei, const int* __restrict__ rank,
    const int* __restrict__ offs, int* __restrict__ srcs)
{
    const int t = blockIdx.x * 256 + threadIdx.x;
    if (t * 4 >= NE) return;
    int4 s = reinterpret_cast<const int4*>(ei)[t];
    int4 d = reinterpret_cast<const int4*>(ei + NE)[t];
    int4 r = reinterpret_cast<const int4*>(rank)[t];
    int p0 = offs[d.x] + r.x;
    int p1 = offs[d.y] + r.y;
    int p2 = offs[d.z] + r.z;
    int p3 = offs[d.w] + r.w;
    srcs[p0] = s.x;
    srcs[p1] = s.y;
    srcs[p2] = s.z;
    srcs[p3] = s.w;
}

// ---------------- gather-reduce: one wave per dst node, bf16 rows ----------
__global__ __launch_bounds__(256) void gather_kernel(
    const uint* __restrict__ xtu,          // xt as bf16 pairs: [NN][64] uints
    const int* __restrict__ offs, const int* __restrict__ srcs,
    float* __restrict__ out)
{
    const int wid = (blockIdx.x * 256 + threadIdx.x) >> 6;
    if (wid >= NN) return;
    const int lane = threadIdx.x & 63;

    uint h = xtu[(size_t)wid * 64 + lane];  // own row (residual)
    float2 acc;
    acc.x = __uint_as_float(h << 16);
    acc.y = __uint_as_float(h & 0xffff0000u);

    int i = offs[wid];
    const int end = offs[wid + 1];

    for (; i + 7 < end; i += 8) {
        uint hv[8];
        #pragma unroll
        for (int k = 0; k < 8; ++k)
            hv[k] = xtu[(size_t)srcs[i + k] * 64 + lane];
        #pragma unroll
        for (int k = 0; k < 8; ++k) {
            acc.x += __uint_as_float(hv[k] << 16);
            acc.y += __uint_as_float(hv[k] & 0xffff0000u);
        }
    }
    for (; i < end; ++i) {
        uint h0 = xtu[(size_t)srcs[i] * 64 + lane];
        acc.x += __uint_as_float(h0 << 16);
        acc.y += __uint_as_float(h0 & 0xffff0000u);
    }
    reinterpret_cast<float2*>(out)[(size_t)wid * 64 + lane] = acc;
}

extern "C" void kernel_launch(void* const* d_in, const int* in_sizes, int n_in,
                              void* d_out, int out_size, void* d_ws, size_t ws_size,
                              hipStream_t stream) {
    const float* x  = (const float*)d_in[0];
    const int*   ei = (const int*)d_in[1];   // [2][NE] int32
    const float* W  = (const float*)d_in[2];
    const float* b  = (const float*)d_in[3];
    float* out = (float*)d_out;

    __bf16* xt   = (__bf16*)d_ws;                     // NN*CH bf16 = 25.6 MB
    int*   cnt   = (int*)(xt + (size_t)NN * CH);      // NN
    int*   loff  = cnt + NN;                          // NN
    int*   offs  = loff + NN;                         // NN+1
    int*   bsums = offs + NN + 1;                     // 128 (+pad to 16B)
    int*   rank  = bsums + 131;                       // NE
    int*   srcs  = rank + NE;                         // NE (last)

    zero_kernel<<<(NN + 255) / 256, 256, 0, stream>>>(cnt);
    gemm_hist_kernel<<<GEMM_BLOCKS + HIST_BLOCKS, 256, 0, stream>>>(
        x, W, b, xt, ei, cnt, rank);
    scan_local_kernel<<<NSCAN, 256, 0, stream>>>(cnt, loff, bsums);
    scan_blocks_kernel<<<1, 128, 0, stream>>>(bsums);
    scan_add_kernel<<<(NN + 1 + 255) / 256, 256, 0, stream>>>(loff, bsums, offs);
    place_kernel<<<HIST_BLOCKS, 256, 0, stream>>>(ei, rank, offs, srcs);
    gather_kernel<<<(NN * 64 + 255) / 256, 256, 0, stream>>>(
        (const uint*)xt, offs, srcs, out);
}

// Round 8
// 112.347 us; speedup vs baseline: 1.1253x; 1.1253x over previous
//
#include <hip/hip_runtime.h>

constexpr int NN = 100000;
constexpr int CH = 128;
constexpr int NE = 625000;
constexpr int NSCAN = (NN + 1023) / 1024;          // 98 scan blocks
constexpr int GEMM_BLOCKS = (NN + 127) / 128;      // 782 (128 rows/block)
constexpr int HIST_BLOCKS = (NE / 4 + 255) / 256;  // 611 (NE % 4 == 0)

typedef __bf16 bf16x8 __attribute__((ext_vector_type(8)));
typedef __bf16 bf16x4 __attribute__((ext_vector_type(4)));
typedef float  f32x4  __attribute__((ext_vector_type(4)));

// ---- fused: MFMA GEMM (blocks < GEMM_BLOCKS) + edge histogram w/ rank ----
// GEMM: xt_bf16 = bf16(x @ W^T + b), 4 waves/block, 32 rows/wave (2 n-tiles).
// A = W (m = channel), B = x (n = node row): D reg-quad = 4 consecutive
// channels of one row -> 8-byte packed stores.
// Hist: rank[e] = atomicAdd(&cnt[dst[e]], 1), 4 edges/thread (ILP-batched).
__global__ __launch_bounds__(256) void gemm_hist_kernel(
    const float* __restrict__ x, const float* __restrict__ W,
    const float* __restrict__ b, __bf16* __restrict__ xt,
    const int* __restrict__ ei, int* __restrict__ cnt, int* __restrict__ rank)
{
    if (blockIdx.x >= GEMM_BLOCKS) {
        const int t = (blockIdx.x - GEMM_BLOCKS) * 256 + threadIdx.x;
        if (t * 4 < NE) {
            int4 d = reinterpret_cast<const int4*>(ei + NE)[t];
            int r0 = atomicAdd(&cnt[d.x], 1);
            int r1 = atomicAdd(&cnt[d.y], 1);
            int r2 = atomicAdd(&cnt[d.z], 1);
            int r3 = atomicAdd(&cnt[d.w], 1);
            reinterpret_cast<int4*>(rank)[t] = make_int4(r0, r1, r2, r3);
        }
        return;
    }

    // W staged as bf16, swizzled: wlds[ch*128 + (k ^ ((ch&7)<<3))]
    __shared__ __bf16 wlds[128 * 128];
    const int tid = threadIdx.x;

    const float4* W4 = reinterpret_cast<const float4*>(W);
    #pragma unroll
    for (int it = 0; it < 16; ++it) {
        int idx = it * 256 + tid;          // 4096 float4 groups, coalesced
        int ch = idx >> 5;
        int k0 = (idx & 31) * 4;
        float4 v = W4[idx];
        __bf16* p = &wlds[ch * 128 + (k0 ^ ((ch & 7) << 3))];
        p[0] = (__bf16)v.x; p[1] = (__bf16)v.y;
        p[2] = (__bf16)v.z; p[3] = (__bf16)v.w;
    }
    __syncthreads();

    const int lane = tid & 63;
    const int lm = lane & 15;          // tile-local row (n) / W channel (m)
    const int lk = lane >> 4;          // k-group / channel-quad selector
    const int row0 = blockIdx.x * 128 + (tid >> 6) * 32;

    const int rowA = row0 + lm;        // n-tile 0
    const int rowB = row0 + 16 + lm;   // n-tile 1
    int ra = rowA < NN ? rowA : NN - 1;
    int rb = rowB < NN ? rowB : NN - 1;
    const float* xrowA = x + (size_t)ra * CH;
    const float* xrowB = x + (size_t)rb * CH;

    bf16x8 bfragA[4], bfragB[4];
    #pragma unroll
    for (int ks = 0; ks < 4; ++ks) {
        const float4* pa = reinterpret_cast<const float4*>(xrowA + ks * 32 + lk * 8);
        const float4* pb = reinterpret_cast<const float4*>(xrowB + ks * 32 + lk * 8);
        float4 u = pa[0], v = pa[1];
        bfragA[ks][0] = (__bf16)u.x; bfragA[ks][1] = (__bf16)u.y;
        bfragA[ks][2] = (__bf16)u.z; bfragA[ks][3] = (__bf16)u.w;
        bfragA[ks][4] = (__bf16)v.x; bfragA[ks][5] = (__bf16)v.y;
        bfragA[ks][6] = (__bf16)v.z; bfragA[ks][7] = (__bf16)v.w;
        u = pb[0]; v = pb[1];
        bfragB[ks][0] = (__bf16)u.x; bfragB[ks][1] = (__bf16)u.y;
        bfragB[ks][2] = (__bf16)u.z; bfragB[ks][3] = (__bf16)u.w;
        bfragB[ks][4] = (__bf16)v.x; bfragB[ks][5] = (__bf16)v.y;
        bfragB[ks][6] = (__bf16)v.z; bfragB[ks][7] = (__bf16)v.w;
    }

    // Bias: lane's channel quad for tile t is t*16 + lk*4 .. +3
    const float4* B4 = reinterpret_cast<const float4*>(b);
    float4 bv[8];
    #pragma unroll
    for (int t = 0; t < 8; ++t) bv[t] = B4[t * 4 + lk];

    const int swz = (lm & 7) << 3;
    #pragma unroll
    for (int t = 0; t < 8; ++t) {
        const int ch = t * 16 + lm;    // A-fragment m index (W channel)
        f32x4 acc0 = {bv[t].x, bv[t].y, bv[t].z, bv[t].w};
        f32x4 acc1 = acc0;
        #pragma unroll
        for (int ks = 0; ks < 4; ++ks) {
            bf16x8 afrag = *reinterpret_cast<const bf16x8*>(
                &wlds[ch * 128 + ((ks * 32 + lk * 8) ^ swz)]);
            acc0 = __builtin_amdgcn_mfma_f32_16x16x32_bf16(afrag, bfragA[ks], acc0, 0, 0, 0);
            acc1 = __builtin_amdgcn_mfma_f32_16x16x32_bf16(afrag, bfragB[ks], acc1, 0, 0, 0);
        }
        // D: col(lane&15) = node row, row((lane>>4)*4+reg) = channel
        const int c0 = t * 16 + lk * 4;
        if (rowA < NN) {
            bf16x4 hv = {(__bf16)acc0[0], (__bf16)acc0[1], (__bf16)acc0[2], (__bf16)acc0[3]};
            *reinterpret_cast<bf16x4*>(&xt[(size_t)rowA * CH + c0]) = hv;
        }
        if (rowB < NN) {
            bf16x4 hv = {(__bf16)acc1[0], (__bf16)acc1[1], (__bf16)acc1[2], (__bf16)acc1[3]};
            *reinterpret_cast<bf16x4*>(&xt[(size_t)rowB * CH + c0]) = hv;
        }
    }
}

// Zero cnt on the compute queue (no SDMA memset node in the graph).
__global__ __launch_bounds__(256) void zero_kernel(int* __restrict__ cnt)
{
    int i = blockIdx.x * 256 + threadIdx.x;
    if (i < NN) cnt[i] = 0;
}

__global__ __launch_bounds__(256) void scan_local_kernel(
    const int* __restrict__ cnt, int* __restrict__ loff,
    int* __restrict__ blocksums)
{
    __shared__ int tsum[256];
    const int t = threadIdx.x;
    const int base = blockIdx.x * 1024 + t * 4;
    int v[4];
    #pragma unroll
    for (int k = 0; k < 4; ++k) {
        int i = base + k;
        v[k] = (i < NN) ? cnt[i] : 0;
    }
    const int s = v[0] + v[1] + v[2] + v[3];
    tsum[t] = s;
    __syncthreads();
    for (int off = 1; off < 256; off <<= 1) {
        int u = (t >= off) ? tsum[t - off] : 0;
        __syncthreads();
        tsum[t] += u;
        __syncthreads();
    }
    int run = tsum[t] - s;
    #pragma unroll
    for (int k = 0; k < 4; ++k) {
        int i = base + k;
        if (i < NN) loff[i] = run;
        run += v[k];
    }
    if (t == 255) blocksums[blockIdx.x] = tsum[255];
}

__global__ __launch_bounds__(128) void scan_blocks_kernel(int* __restrict__ blocksums)
{
    __shared__ int sm[128];
    const int t = threadIdx.x;
    int v = (t < NSCAN) ? blocksums[t] : 0;
    sm[t] = v;
    __syncthreads();
    for (int off = 1; off < 128; off <<= 1) {
        int u = (t >= off) ? sm[t - off] : 0;
        __syncthreads();
        sm[t] += u;
        __syncthreads();
    }
    if (t < NSCAN) blocksums[t] = sm[t] - v;
}

__global__ __launch_bounds__(256) void scan_add_kernel(
    const int* __restrict__ loff, const int* __restrict__ blocksums,
    int* __restrict__ offs)
{
    int i = blockIdx.x * 256 + threadIdx.x;
    if (i > NN) return;
    if (i == NN) { offs[NN] = NE; return; }
    offs[i] = loff[i] + blocksums[i >> 10];
}

// Atomic-free placement: srcs[offs[dst] + rank[e]] = src, 4 edges/thread.
__global__ __launch_bounds__(256) void place_kernel(
    const int* __restrict__ ei, const int* __restrict__ rank,
    const int* __restrict__ offs, int* __restrict__ srcs)
{
    const int t = blockIdx.x * 256 + threadIdx.x;
    if (t * 4 >= NE) return;
    int4 s = reinterpret_cast<const int4*>(ei)[t];
    int4 d = reinterpret_cast<const int4*>(ei + NE)[t];
    int4 r = reinterpret_cast<const int4*>(rank)[t];
    int p0 = offs[d.x] + r.x;
    int p1 = offs[d.y] + r.y;
    int p2 = offs[d.z] + r.z;
    int p3 = offs[d.w] + r.w;
    srcs[p0] = s.x;
    srcs[p1] = s.y;
    srcs[p2] = s.z;
    srcs[p3] = s.w;
}

// ---- gather-reduce: one wave per dst node, cooperative index staging ----
// Lane l loads srcs[beg+l] (one coalesced load covers up to 64 edges);
// inner loop broadcasts index k via __shfl (wave-uniform k -> v_readlane,
// no memory latency on the index path). Row loads issue 4-deep.
__global__ __launch_bounds__(256) void gather_kernel(
    const uint* __restrict__ xtu,          // xt as bf16 pairs: [NN][64] uints
    const int* __restrict__ offs, const int* __restrict__ srcs,
    float* __restrict__ out)
{
    const int wid = (blockIdx.x * 256 + threadIdx.x) >> 6;
    if (wid >= NN) return;
    const int lane = threadIdx.x & 63;

    uint h = xtu[(size_t)wid * 64 + lane];  // own row (residual)
    float2 acc;
    acc.x = __uint_as_float(h << 16);
    acc.y = __uint_as_float(h & 0xffff0000u);

    int beg = offs[wid];
    const int end = offs[wid + 1];

    while (beg < end) {
        const int n = min(end - beg, 64);
        const int myidx = (lane < n) ? srcs[beg + lane] : 0;
        int k = 0;
        for (; k + 3 < n; k += 4) {
            int s0 = __shfl(myidx, k);
            int s1 = __shfl(myidx, k + 1);
            int s2 = __shfl(myidx, k + 2);
            int s3 = __shfl(myidx, k + 3);
            uint h0 = xtu[(size_t)s0 * 64 + lane];
            uint h1 = xtu[(size_t)s1 * 64 + lane];
            uint h2 = xtu[(size_t)s2 * 64 + lane];
            uint h3 = xtu[(size_t)s3 * 64 + lane];
            acc.x += __uint_as_float(h0 << 16);  acc.y += __uint_as_float(h0 & 0xffff0000u);
            acc.x += __uint_as_float(h1 << 16);  acc.y += __uint_as_float(h1 & 0xffff0000u);
            acc.x += __uint_as_float(h2 << 16);  acc.y += __uint_as_float(h2 & 0xffff0000u);
            acc.x += __uint_as_float(h3 << 16);  acc.y += __uint_as_float(h3 & 0xffff0000u);
        }
        for (; k < n; ++k) {
            int s0 = __shfl(myidx, k);
            uint h0 = xtu[(size_t)s0 * 64 + lane];
            acc.x += __uint_as_float(h0 << 16);
            acc.y += __uint_as_float(h0 & 0xffff0000u);
        }
        beg += n;
    }
    reinterpret_cast<float2*>(out)[(size_t)wid * 64 + lane] = acc;
}

extern "C" void kernel_launch(void* const* d_in, const int* in_sizes, int n_in,
                              void* d_out, int out_size, void* d_ws, size_t ws_size,
                              hipStream_t stream) {
    const float* x  = (const float*)d_in[0];
    const int*   ei = (const int*)d_in[1];   // [2][NE] int32
    const float* W  = (const float*)d_in[2];
    const float* b  = (const float*)d_in[3];
    float* out = (float*)d_out;

    __bf16* xt   = (__bf16*)d_ws;                     // NN*CH bf16 = 25.6 MB
    int*   cnt   = (int*)(xt + (size_t)NN * CH);      // NN
    int*   loff  = cnt + NN;                          // NN
    int*   offs  = loff + NN;                         // NN+1
    int*   bsums = offs + NN + 1;                     // 128 (+pad to 16B)
    int*   rank  = bsums + 131;                       // NE
    int*   srcs  = rank + NE;                         // NE (last)

    zero_kernel<<<(NN + 255) / 256, 256, 0, stream>>>(cnt);
    gemm_hist_kernel<<<GEMM_BLOCKS + HIST_BLOCKS, 256, 0, stream>>>(
        x, W, b, xt, ei, cnt, rank);
    scan_local_kernel<<<NSCAN, 256, 0, stream>>>(cnt, loff, bsums);
    scan_blocks_kernel<<<1, 128, 0, stream>>>(bsums);
    scan_add_kernel<<<(NN + 1 + 255) / 256, 256, 0, stream>>>(loff, bsums, offs);
    place_kernel<<<HIST_BLOCKS, 256, 0, stream>>>(ei, rank, offs, srcs);
    gather_kernel<<<(NN * 64 + 255) / 256, 256, 0, stream>>>(
        (const uint*)xt, offs, srcs, out);
}

// Round 9
// 108.346 us; speedup vs baseline: 1.1668x; 1.0369x over previous
//
#include <hip/hip_runtime.h>

constexpr int NN = 100000;
constexpr int CH = 128;
constexpr int NE = 625000;
constexpr int NSCAN = (NN + 1023) / 1024;          // 98 scan blocks
constexpr int GEMM_BLOCKS = (NN + 255) / 256;      // 391 (256 rows/block)
constexpr int HIST_BLOCKS = NE / 8 / 256 + 1;      // 306 (8 edges/thread)
constexpr int ZERO_BLOCKS = (NN + 255) / 256;      // 391
constexpr int WCONV_BLOCKS = 16;                   // 16384 elems / 1024

typedef __bf16 bf16x8 __attribute__((ext_vector_type(8)));
typedef __bf16 bf16x4 __attribute__((ext_vector_type(4)));
typedef float  f32x4  __attribute__((ext_vector_type(4)));

// ---- fused: zero cnt + convert W to bf16 (once per launch) ----
__global__ __launch_bounds__(256) void zero_wconv_kernel(
    int* __restrict__ cnt, const float* __restrict__ W, __bf16* __restrict__ Wb)
{
    if (blockIdx.x < ZERO_BLOCKS) {
        int i = blockIdx.x * 256 + threadIdx.x;
        if (i < NN) cnt[i] = 0;
        return;
    }
    int i = (blockIdx.x - ZERO_BLOCKS) * 256 + threadIdx.x;   // float4 group
    float4 v = reinterpret_cast<const float4*>(W)[i];
    bf16x4 h = {(__bf16)v.x, (__bf16)v.y, (__bf16)v.z, (__bf16)v.w};
    reinterpret_cast<bf16x4*>(Wb)[i] = h;
}

// ---- fused: MFMA GEMM (blocks < GEMM_BLOCKS) + edge histogram w/ rank ----
// GEMM: no LDS. A = W (m = channel) loaded straight from L2-resident Wb
// (16B/lane), B = x (n = node row), 4 n-tiles/wave = 64 rows/wave.
// D reg-quad = 4 consecutive channels of one row -> 8-byte packed stores.
// Hist: rank[e] = atomicAdd(&cnt[dst[e]], 1), 8 edges/thread (ILP-batched).
__global__ __launch_bounds__(256) void gemm_hist_kernel(
    const float* __restrict__ x, const __bf16* __restrict__ Wb,
    const float* __restrict__ b, __bf16* __restrict__ xt,
    const int* __restrict__ ei, int* __restrict__ cnt, int* __restrict__ rank)
{
    if (blockIdx.x >= GEMM_BLOCKS) {
        const int t = (blockIdx.x - GEMM_BLOCKS) * 256 + threadIdx.x;
        if (t * 8 < NE) {
            int4 d0 = reinterpret_cast<const int4*>(ei + NE)[t * 2];
            int4 d1 = reinterpret_cast<const int4*>(ei + NE)[t * 2 + 1];
            int r0 = atomicAdd(&cnt[d0.x], 1);
            int r1 = atomicAdd(&cnt[d0.y], 1);
            int r2 = atomicAdd(&cnt[d0.z], 1);
            int r3 = atomicAdd(&cnt[d0.w], 1);
            int r4 = atomicAdd(&cnt[d1.x], 1);
            int r5 = atomicAdd(&cnt[d1.y], 1);
            int r6 = atomicAdd(&cnt[d1.z], 1);
            int r7 = atomicAdd(&cnt[d1.w], 1);
            reinterpret_cast<int4*>(rank)[t * 2]     = make_int4(r0, r1, r2, r3);
            reinterpret_cast<int4*>(rank)[t * 2 + 1] = make_int4(r4, r5, r6, r7);
        }
        return;
    }

    const int tid  = threadIdx.x;
    const int lane = tid & 63;
    const int lm = lane & 15;          // tile-local row (n) / W channel (m)
    const int lk = lane >> 4;          // k-group / channel-quad selector
    const int row0 = blockIdx.x * 256 + (tid >> 6) * 64;

    int rows[4], rc[4];
    #pragma unroll
    for (int tl = 0; tl < 4; ++tl) {
        rows[tl] = row0 + tl * 16 + lm;
        rc[tl] = rows[tl] < NN ? rows[tl] : NN - 1;
    }

    // x fragments: 4 tiles x 4 k-steps, 8 bf16 each
    bf16x8 bfrag[4][4];
    #pragma unroll
    for (int tl = 0; tl < 4; ++tl) {
        const float* xrow = x + (size_t)rc[tl] * CH;
        #pragma unroll
        for (int ks = 0; ks < 4; ++ks) {
            const float4* p = reinterpret_cast<const float4*>(xrow + ks * 32 + lk * 8);
            float4 u = p[0], v = p[1];
            bfrag[tl][ks][0] = (__bf16)u.x; bfrag[tl][ks][1] = (__bf16)u.y;
            bfrag[tl][ks][2] = (__bf16)u.z; bfrag[tl][ks][3] = (__bf16)u.w;
            bfrag[tl][ks][4] = (__bf16)v.x; bfrag[tl][ks][5] = (__bf16)v.y;
            bfrag[tl][ks][6] = (__bf16)v.z; bfrag[tl][ks][7] = (__bf16)v.w;
        }
    }

    // Bias: lane's channel quad for tile t is t*16 + lk*4 .. +3
    const float4* B4 = reinterpret_cast<const float4*>(b);

    #pragma unroll
    for (int t = 0; t < 8; ++t) {
        const int ch = t * 16 + lm;    // A-fragment m index (W channel)
        float4 bv = B4[t * 4 + lk];
        f32x4 acc0 = {bv.x, bv.y, bv.z, bv.w};
        f32x4 acc1 = acc0, acc2 = acc0, acc3 = acc0;
        #pragma unroll
        for (int ks = 0; ks < 4; ++ks) {
            bf16x8 afrag = *reinterpret_cast<const bf16x8*>(
                Wb + ch * 128 + ks * 32 + lk * 8);
            acc0 = __builtin_amdgcn_mfma_f32_16x16x32_bf16(afrag, bfrag[0][ks], acc0, 0, 0, 0);
            acc1 = __builtin_amdgcn_mfma_f32_16x16x32_bf16(afrag, bfrag[1][ks], acc1, 0, 0, 0);
            acc2 = __builtin_amdgcn_mfma_f32_16x16x32_bf16(afrag, bfrag[2][ks], acc2, 0, 0, 0);
            acc3 = __builtin_amdgcn_mfma_f32_16x16x32_bf16(afrag, bfrag[3][ks], acc3, 0, 0, 0);
        }
        // D: col(lane&15) = node row, row((lane>>4)*4+reg) = channel
        const int c0 = t * 16 + lk * 4;
        f32x4 av[4] = {acc0, acc1, acc2, acc3};
        #pragma unroll
        for (int tl = 0; tl < 4; ++tl) {
            if (rows[tl] < NN) {
                bf16x4 hv = {(__bf16)av[tl][0], (__bf16)av[tl][1],
                             (__bf16)av[tl][2], (__bf16)av[tl][3]};
                *reinterpret_cast<bf16x4*>(&xt[(size_t)rows[tl] * CH + c0]) = hv;
            }
        }
    }
}

__global__ __launch_bounds__(256) void scan_local_kernel(
    const int* __restrict__ cnt, int* __restrict__ loff,
    int* __restrict__ blocksums)
{
    __shared__ int tsum[256];
    const int t = threadIdx.x;
    const int base = blockIdx.x * 1024 + t * 4;
    int v[4];
    #pragma unroll
    for (int k = 0; k < 4; ++k) {
        int i = base + k;
        v[k] = (i < NN) ? cnt[i] : 0;
    }
    const int s = v[0] + v[1] + v[2] + v[3];
    tsum[t] = s;
    __syncthreads();
    for (int off = 1; off < 256; off <<= 1) {
        int u = (t >= off) ? tsum[t - off] : 0;
        __syncthreads();
        tsum[t] += u;
        __syncthreads();
    }
    int run = tsum[t] - s;
    #pragma unroll
    for (int k = 0; k < 4; ++k) {
        int i = base + k;
        if (i < NN) loff[i] = run;
        run += v[k];
    }
    if (t == 255) blocksums[blockIdx.x] = tsum[255];
}

__global__ __launch_bounds__(128) void scan_blocks_kernel(int* __restrict__ blocksums)
{
    __shared__ int sm[128];
    const int t = threadIdx.x;
    int v = (t < NSCAN) ? blocksums[t] : 0;
    sm[t] = v;
    __syncthreads();
    for (int off = 1; off < 128; off <<= 1) {
        int u = (t >= off) ? sm[t - off] : 0;
        __syncthreads();
        sm[t] += u;
        __syncthreads();
    }
    if (t < NSCAN) blocksums[t] = sm[t] - v;
}

__global__ __launch_bounds__(256) void scan_add_kernel(
    const int* __restrict__ loff, const int* __restrict__ blocksums,
    int* __restrict__ offs)
{
    int i = blockIdx.x * 256 + threadIdx.x;
    if (i > NN) return;
    if (i == NN) { offs[NN] = NE; return; }
    offs[i] = loff[i] + blocksums[i >> 10];
}

// Atomic-free placement: srcs[offs[dst] + rank[e]] = src, 4 edges/thread.
__global__ __launch_bounds__(256) void place_kernel(
    const int* __restrict__ ei, const int* __restrict__ rank,
    const int* __restrict__ offs, int* __restrict__ srcs)
{
    const int t = blockIdx.x * 256 + threadIdx.x;
    if (t * 4 >= NE) return;
    int4 s = reinterpret_cast<const int4*>(ei)[t];
    int4 d = reinterpret_cast<const int4*>(ei + NE)[t];
    int4 r = reinterpret_cast<const int4*>(rank)[t];
    int p0 = offs[d.x] + r.x;
    int p1 = offs[d.y] + r.y;
    int p2 = offs[d.z] + r.z;
    int p3 = offs[d.w] + r.w;
    srcs[p0] = s.x;
    srcs[p1] = s.y;
    srcs[p2] = s.z;
    srcs[p3] = s.w;
}

// ---- gather-reduce: one wave per dst node, cooperative index staging ----
__global__ __launch_bounds__(256) void gather_kernel(
    const uint* __restrict__ xtu,          // xt as bf16 pairs: [NN][64] uints
    const int* __restrict__ offs, const int* __restrict__ srcs,
    float* __restrict__ out)
{
    const int wid = (blockIdx.x * 256 + threadIdx.x) >> 6;
    if (wid >= NN) return;
    const int lane = threadIdx.x & 63;

    uint h = xtu[(size_t)wid * 64 + lane];  // own row (residual)
    float2 acc;
    acc.x = __uint_as_float(h << 16);
    acc.y = __uint_as_float(h & 0xffff0000u);

    int beg = offs[wid];
    const int end = offs[wid + 1];

    while (beg < end) {
        const int n = min(end - beg, 64);
        const int myidx = (lane < n) ? srcs[beg + lane] : 0;
        int k = 0;
        for (; k + 3 < n; k += 4) {
            int s0 = __shfl(myidx, k);
            int s1 = __shfl(myidx, k + 1);
            int s2 = __shfl(myidx, k + 2);
            int s3 = __shfl(myidx, k + 3);
            uint h0 = xtu[(size_t)s0 * 64 + lane];
            uint h1 = xtu[(size_t)s1 * 64 + lane];
            uint h2 = xtu[(size_t)s2 * 64 + lane];
            uint h3 = xtu[(size_t)s3 * 64 + lane];
            acc.x += __uint_as_float(h0 << 16);  acc.y += __uint_as_float(h0 & 0xffff0000u);
            acc.x += __uint_as_float(h1 << 16);  acc.y += __uint_as_float(h1 & 0xffff0000u);
            acc.x += __uint_as_float(h2 << 16);  acc.y += __uint_as_float(h2 & 0xffff0000u);
            acc.x += __uint_as_float(h3 << 16);  acc.y += __uint_as_float(h3 & 0xffff0000u);
        }
        for (; k < n; ++k) {
            int s0 = __shfl(myidx, k);
            uint h0 = xtu[(size_t)s0 * 64 + lane];
            acc.x += __uint_as_float(h0 << 16);
            acc.y += __uint_as_float(h0 & 0xffff0000u);
        }
        beg += n;
    }
    reinterpret_cast<float2*>(out)[(size_t)wid * 64 + lane] = acc;
}

extern "C" void kernel_launch(void* const* d_in, const int* in_sizes, int n_in,
                              void* d_out, int out_size, void* d_ws, size_t ws_size,
                              hipStream_t stream) {
    const float* x  = (const float*)d_in[0];
    const int*   ei = (const int*)d_in[1];   // [2][NE] int32
    const float* W  = (const float*)d_in[2];
    const float* b  = (const float*)d_in[3];
    float* out = (float*)d_out;

    __bf16* xt   = (__bf16*)d_ws;                     // NN*CH bf16 = 25.6 MB
    int*   cnt   = (int*)(xt + (size_t)NN * CH);      // NN
    int*   loff  = cnt + NN;                          // NN
    int*   offs  = loff + NN;                         // NN+1
    int*   bsums = offs + NN + 1;                     // 131
    int*   rank  = bsums + 131;                       // NE
    int*   srcs  = rank + NE;                         // NE
    __bf16* Wb   = (__bf16*)(srcs + NE);              // 16384 bf16 (16B-aligned)

    zero_wconv_kernel<<<ZERO_BLOCKS + WCONV_BLOCKS, 256, 0, stream>>>(cnt, W, Wb);
    gemm_hist_kernel<<<GEMM_BLOCKS + HIST_BLOCKS, 256, 0, stream>>>(
        x, Wb, b, xt, ei, cnt, rank);
    scan_local_kernel<<<NSCAN, 256, 0, stream>>>(cnt, loff, bsums);
    scan_blocks_kernel<<<1, 128, 0, stream>>>(bsums);
    scan_add_kernel<<<(NN + 1 + 255) / 256, 256, 0, stream>>>(loff, bsums, offs);
    place_kernel<<<(NE / 4 + 255) / 256, 256, 0, stream>>>(ei, rank, offs, srcs);
    gather_kernel<<<(NN * 64 + 255) / 256, 256, 0, stream>>>(
        (const uint*)xt, offs, srcs, out);
}